// Round 4
// baseline (480.156 us; speedup 1.0000x reference)
//
#include <hip/hip_runtime.h>

// HopAttentionLayer: B=256, T=64, N=2048, D=128, fp32.
// attention[b,n] = softmax_n( T * dot(context[b,n,:], W[D:2D]) )
//   (tgt_term[b] and T*b0 are constant over n -> cancel in softmax)
// out[b,n,d] = attention[b,n] * context[b,n,d]
//
// R3: chunked 2-kernel pipeline. 4 chunks x 64 batches (64 MiB ctx each,
// 1/4 of L3): scores(chunk) then softmax+scale(chunk) immediately after,
// so the scale pass re-reads ctx from Infinity Cache, not HBM.
//  - softmax fused into the scale kernel (each block redundantly reduces
//    its batch's 2048 scores: 8 KiB L2-hot read + ~60 VALU -> trivial)
//  - scale pass walks its chunk in reverse (LIFO vs score pass stream)
//  - nt stores: output write doesn't evict chunk ctx from L2/L3

#define B_DIM  256
#define N_DIM  2048
#define D_DIM  128
#define DVEC   (D_DIM / 4)    // 32 float4 per row
#define T_SCALE 64.0f
#define CHUNK  64             // batches per chunk (64 MiB of ctx)

typedef float f4v __attribute__((ext_vector_type(4)));

// ---- A: scores[r] = T * dot(ctx[r,:], Wc) for r in chunk ----
// 256 threads = 4 waves = 8 rows/block; one float4 load per thread.
// Normal (caching) loads: this pass populates L2/L3 for the scale pass.
__global__ __launch_bounds__(256)
void k_scores(const float* __restrict__ ctx, const float* __restrict__ W,
              float* __restrict__ scores, int row_base) {
    const int tid  = threadIdx.x;
    const int wave = tid >> 6;
    const int lane = tid & 63;
    const int sub  = lane & 31;
    const int half = lane >> 5;
    const size_t r = (size_t)row_base + blockIdx.x * 8 + wave * 2 + half;

    const float4 wc = ((const float4*)(W + D_DIM))[sub];
    const float4 v  = ((const float4*)ctx)[r * DVEC + sub];
    float p = v.x * wc.x + v.y * wc.y + v.z * wc.z + v.w * wc.w;
    #pragma unroll
    for (int m = 1; m < 32; m <<= 1) p += __shfl_xor(p, m, 64);  // in-half
    if (sub == 0) scores[r] = T_SCALE * p;
}

// ---- B: per-batch softmax (redundant per block) + scale + write ----
// gridDim.x = CHUNK*32 blocks; each handles 64 rows (1/32) of one batch.
// Processed in reverse (LIFO) so the most-recently-streamed ctx is hit
// first in L3.
__global__ __launch_bounds__(256)
void k_softmax_scale(const float* __restrict__ ctx,
                     const float* __restrict__ scores,
                     float* __restrict__ out, int batch_base) {
    const int tid  = threadIdx.x;
    const int wave = tid >> 6;
    const int lane = tid & 63;
    const int rb   = gridDim.x - 1 - blockIdx.x;   // reverse walk
    const int b    = batch_base + (rb >> 5);       // batch
    const int seg  = rb & 31;                      // 64-row segment in batch

    const float* s = scores + (size_t)b * N_DIM;

    __shared__ float red[4];
    __shared__ float sp[64];

    // -- block max over the batch's 2048 scores (8/thread) --
    const float4 a = ((const float4*)s)[tid];
    const float4 c = ((const float4*)s)[tid + 256];
    float m0 = fmaxf(fmaxf(fmaxf(a.x, a.y), fmaxf(a.z, a.w)),
                     fmaxf(fmaxf(c.x, c.y), fmaxf(c.z, c.w)));
    #pragma unroll
    for (int m = 1; m < 64; m <<= 1) m0 = fmaxf(m0, __shfl_xor(m0, m, 64));
    if (lane == 0) red[wave] = m0;
    __syncthreads();
    const float gmax = fmaxf(fmaxf(red[0], red[1]), fmaxf(red[2], red[3]));
    __syncthreads();

    // -- block sum of exp --
    float sum = __expf(a.x - gmax) + __expf(a.y - gmax)
              + __expf(a.z - gmax) + __expf(a.w - gmax)
              + __expf(c.x - gmax) + __expf(c.y - gmax)
              + __expf(c.z - gmax) + __expf(c.w - gmax);
    #pragma unroll
    for (int m = 1; m < 64; m <<= 1) sum += __shfl_xor(sum, m, 64);
    if (lane == 0) red[wave] = sum;
    __syncthreads();
    const float inv = 1.0f / (red[0] + red[1] + red[2] + red[3]);

    // -- p for this block's 64 rows --
    if (tid < 64) sp[tid] = __expf(s[seg * 64 + tid] - gmax) * inv;
    __syncthreads();

    // -- scale & write: 64 rows = 2048 float4, 8 per thread, coalesced --
    const size_t base_row = (size_t)b * N_DIM + seg * 64;
    const f4v* c4 = (const f4v*)ctx + base_row * DVEC;
    f4v*       o4 = (f4v*)out       + base_row * DVEC;
    #pragma unroll
    for (int i = 0; i < 8; ++i) {
        const int f = i * 256 + tid;
        f4v v = c4[f];
        v *= sp[f >> 5];
        __builtin_nontemporal_store(v, &o4[f]);
    }
}

extern "C" void kernel_launch(void* const* d_in, const int* in_sizes, int n_in,
                              void* d_out, int out_size, void* d_ws, size_t ws_size,
                              hipStream_t stream) {
    (void)in_sizes; (void)n_in; (void)out_size; (void)ws_size;
    // d_in[0] = targetsentence_emb (unused: cancels in softmax)
    // d_in[1] = context_emb, d_in[2] = W, d_in[3] = b (unused: cancels)
    const float* ctx = (const float*)d_in[1];
    const float* W   = (const float*)d_in[2];
    float* out       = (float*)d_out;
    float* scores    = (float*)d_ws;   // B*N floats = 2 MiB

    for (int c = 0; c < B_DIM / CHUNK; ++c) {
        const int batch_base = c * CHUNK;
        const int row_base   = batch_base * N_DIM;
        hipLaunchKernelGGL(k_scores, dim3(CHUNK * N_DIM / 8), dim3(256), 0,
                           stream, ctx, W, scores, row_base);
        hipLaunchKernelGGL(k_softmax_scale, dim3(CHUNK * 32), dim3(256), 0,
                           stream, ctx, scores, out, batch_base);
    }
}